// Round 5
// baseline (92.102 us; speedup 1.0000x reference)
//
#include <hip/hip_runtime.h>

#define NN 2048
#define KK 32

typedef __attribute__((ext_vector_type(8)))  short short8;   // 8 x bf16
typedef __attribute__((ext_vector_type(4)))  float f32x4;

// workspace (bytes):
//  t_part: [512 blk][32 b][512 n] f32   32 MiB @ 0
//  s_part: [512 blk][32 b][512 n] f32   32 MiB @ 33554432
//  t     : [32 b][32 k][16 z]   f32     64 KiB @ 67108864
#define WS_TPART 0UL
#define WS_SPART 33554432UL
#define WS_T     67108864UL
#define WS_NEED  67174400UL

__device__ __forceinline__ short8 pack8(const float* r) {
    short8 o;
#pragma unroll
    for (int e = 0; e < 8; ++e)
        o[e] = (short)(unsigned short)((__float_as_uint(r[e]) + 0x8000u) >> 16);
    return o;
}

__device__ __forceinline__ short8 sel8(bool keep, short8 v) {
    union { short8 s; unsigned u[4]; } a, b;
    a.s = v;
#pragma unroll
    for (int i = 0; i < 4; ++i) b.u[i] = keep ? a.u[i] : 0u;
    return b.s;
}

// ---------------- kA: t partials = sum_j (x @ w) via MFMA -------------------
// grid 512 (4 j per block), block 256 = 4 waves; wave wv owns k in [8wv, 8wv+8).
// MFMA 16x16x32 bf16: A = x[b][K=(j-pair,i)], B = w[(j-pair,i)][kz], C = t-part.
// lane l: z = l&15, g = l>>4; A row = l&15 (b within m-tile); K idx = g*8+e
//   -> j-half jl = g>>1, i-half ih = g&1. C: col = l&15 (z), row = g*4 + r (b).
__global__ __launch_bounds__(256)
void kA(const float* __restrict__ x, const float* __restrict__ w,
        float* __restrict__ t_part)
{
    const int tid = threadIdx.x;
    const int wv  = tid >> 6, l = tid & 63;
    const int z   = l & 15,  g = l >> 4;
    const int jl  = g >> 1,  ih = g & 1;
    const int j0  = blockIdx.x * 4;

    f32x4 C[2][8];
#pragma unroll
    for (int m = 0; m < 2; ++m)
#pragma unroll
        for (int tt = 0; tt < 8; ++tt) C[m][tt] = (f32x4){0.f, 0.f, 0.f, 0.f};

#pragma unroll
    for (int p = 0; p < 2; ++p) {
        const int jp = j0 + p * 2 + jl;

        // A fragments: x[b][jp][ih*8 + e], b = m*16 + z
        short8 Af[2];
#pragma unroll
        for (int m = 0; m < 2; ++m) {
            const float* xp = x + ((size_t)(m * 16 + z) * NN + jp) * 16 + ih * 8;
            float ar[8];
            float4 v0 = *reinterpret_cast<const float4*>(xp);
            float4 v1 = *reinterpret_cast<const float4*>(xp + 4);
            ar[0]=v0.x; ar[1]=v0.y; ar[2]=v0.z; ar[3]=v0.w;
            ar[4]=v1.x; ar[5]=v1.y; ar[6]=v1.z; ar[7]=v1.w;
            Af[m] = pack8(ar);
        }

        // B fragments: w[k][jp][ih*8+e][z], 8 strided dword loads per tile
        short8 Bf[8];
#pragma unroll
        for (int tg = 0; tg < 2; ++tg) {
            float br[4][8];
#pragma unroll
            for (int q = 0; q < 4; ++q) {
                const int k = wv * 8 + tg * 4 + q;
                const float* wp = w + (size_t)(k * NN + jp) * 256 + ih * 128 + z;
#pragma unroll
                for (int e = 0; e < 8; ++e) br[q][e] = wp[e * 16];
            }
#pragma unroll
            for (int q = 0; q < 4; ++q) Bf[tg * 4 + q] = pack8(br[q]);
        }

#pragma unroll
        for (int tt = 0; tt < 8; ++tt)
#pragma unroll
            for (int m = 0; m < 2; ++m)
                C[m][tt] = __builtin_amdgcn_mfma_f32_16x16x32_bf16(
                    Af[m], Bf[tt], C[m][tt], 0, 0, 0);
    }

    float* tp = t_part + (size_t)blockIdx.x * 16384;
#pragma unroll
    for (int m = 0; m < 2; ++m)
#pragma unroll
        for (int tt = 0; tt < 8; ++tt)
#pragma unroll
            for (int r = 0; r < 4; ++r)
                tp[(size_t)(m * 16 + g * 4 + r) * 512 + (wv * 8 + tt) * 16 + z] =
                    C[m][tt][r];
}

// ---------------- kred_t: reduce 512 t partials -> t ------------------------
// grid 256, block 256: col c = blk*16 + (tid&15) (f32x4 cols), chunk = tid>>4.
__global__ __launch_bounds__(256)
void kred_t(const float* __restrict__ t_part, float* __restrict__ t)
{
    __shared__ f32x4 red[16][16];
    const int tid = threadIdx.x;
    const int c   = blockIdx.x * 16 + (tid & 15);
    const int ch  = tid >> 4;
    const f32x4* P = reinterpret_cast<const f32x4*>(t_part);
    f32x4 a = (f32x4){0.f, 0.f, 0.f, 0.f};
#pragma unroll 4
    for (int q = 0; q < 32; ++q) a += P[(size_t)(ch * 32 + q) * 4096 + c];
    red[ch][tid & 15] = a;
    __syncthreads();
    if (tid < 16) {
        f32x4 s = (f32x4){0.f, 0.f, 0.f, 0.f};
#pragma unroll
        for (int r = 0; r < 16; ++r) s += red[r][tid];
        reinterpret_cast<f32x4*>(t)[blockIdx.x * 16 + tid] = s;
    }
}

// ---------------- kB: recompute u, logits, softmax, s partials --------------
// grid 512 (4 j), block 256. Same fragment mechanics as kA; per j the B
// operand's other j-half is zero-masked so MFMA yields u for that j only.
__global__ __launch_bounds__(256)
void kB(const float* __restrict__ x, const float* __restrict__ w,
        const float* __restrict__ t, const float* __restrict__ bias,
        float* __restrict__ s_part)
{
    __shared__ float t_lds[16384];        // [b][k][z]
    __shared__ float l_lds[32][33];
    __shared__ float c_lds[32][33];
    __shared__ float b_lds[32][4];
    const int tid = threadIdx.x;
    const int wv  = tid >> 6, l = tid & 63;
    const int z   = l & 15,  g = l >> 4;
    const int jl  = g >> 1,  ih = g & 1;
    const int j0  = blockIdx.x * 4;

#pragma unroll
    for (int q = 0; q < 16; ++q)
        reinterpret_cast<f32x4*>(t_lds)[q * 256 + tid] =
            reinterpret_cast<const f32x4*>(t)[q * 256 + tid];
    if (tid < 128) b_lds[tid >> 2][tid & 3] = bias[(size_t)(tid >> 2) * NN + j0 + (tid & 3)];
    __syncthreads();

    f32x4 S[2][8];
#pragma unroll
    for (int m = 0; m < 2; ++m)
#pragma unroll
        for (int tt = 0; tt < 8; ++tt) S[m][tt] = (f32x4){0.f, 0.f, 0.f, 0.f};

#pragma unroll 1
    for (int p = 0; p < 2; ++p) {
        const int jp = j0 + p * 2 + jl;

        short8 Af[2];
#pragma unroll
        for (int m = 0; m < 2; ++m) {
            const float* xp = x + ((size_t)(m * 16 + z) * NN + jp) * 16 + ih * 8;
            float ar[8];
            float4 v0 = *reinterpret_cast<const float4*>(xp);
            float4 v1 = *reinterpret_cast<const float4*>(xp + 4);
            ar[0]=v0.x; ar[1]=v0.y; ar[2]=v0.z; ar[3]=v0.w;
            ar[4]=v1.x; ar[5]=v1.y; ar[6]=v1.z; ar[7]=v1.w;
            Af[m] = pack8(ar);
        }
        short8 Bf[8];
#pragma unroll
        for (int tg = 0; tg < 2; ++tg) {
            float br[4][8];
#pragma unroll
            for (int q = 0; q < 4; ++q) {
                const int k = wv * 8 + tg * 4 + q;
                const float* wp = w + (size_t)(k * NN + jp) * 256 + ih * 128 + z;
#pragma unroll
                for (int e = 0; e < 8; ++e) br[q][e] = wp[e * 16];
            }
#pragma unroll
            for (int q = 0; q < 4; ++q) Bf[tg * 4 + q] = pack8(br[q]);
        }

#pragma unroll 1
        for (int jj = 0; jj < 2; ++jj) {
            const bool keep = (jl == jj);
            f32x4 C[2][8];
            const f32x4 z4 = (f32x4){0.f, 0.f, 0.f, 0.f};
#pragma unroll
            for (int tt = 0; tt < 8; ++tt) {
                short8 bj = sel8(keep, Bf[tt]);
#pragma unroll
                for (int m = 0; m < 2; ++m)
                    C[m][tt] = __builtin_amdgcn_mfma_f32_16x16x32_bf16(
                        Af[m], bj, z4, 0, 0, 0);
            }
            // logits: per (m,tt,r): sum_z C * t ; butterfly over the 16-lane z group
#pragma unroll
            for (int m = 0; m < 2; ++m)
#pragma unroll
                for (int tt = 0; tt < 8; ++tt) {
                    const int k = wv * 8 + tt;
                    float red[4];
#pragma unroll
                    for (int r = 0; r < 4; ++r) {
                        float pv = C[m][tt][r] *
                            t_lds[(size_t)(m * 16 + g * 4 + r) * 512 + k * 16 + z];
                        pv += __shfl_xor(pv, 1);
                        pv += __shfl_xor(pv, 2);
                        pv += __shfl_xor(pv, 4);
                        pv += __shfl_xor(pv, 8);
                        red[r] = pv;
                    }
                    if (z == ((tt << 1) | m)) {
#pragma unroll
                        for (int r = 0; r < 4; ++r)
                            l_lds[m * 16 + g * 4 + r][k] = red[r];
                    }
                }
            __syncthreads();
            // softmax over k (32), threads = 32 b x 8 kq
            {
                const int bb = tid >> 3, kq = tid & 7;
                float lv[4];
#pragma unroll
                for (int m4 = 0; m4 < 4; ++m4) lv[m4] = l_lds[bb][kq * 4 + m4];
                float pm = fmaxf(fmaxf(lv[0], lv[1]), fmaxf(lv[2], lv[3]));
                pm = fmaxf(pm, __shfl_xor(pm, 1));
                pm = fmaxf(pm, __shfl_xor(pm, 2));
                pm = fmaxf(pm, __shfl_xor(pm, 4));
                float ev[4], ps = 0.f;
#pragma unroll
                for (int m4 = 0; m4 < 4; ++m4) {
                    ev[m4] = __expf((lv[m4] - pm) * 0.25f);
                    ps += ev[m4];
                }
                ps += __shfl_xor(ps, 1);
                ps += __shfl_xor(ps, 2);
                ps += __shfl_xor(ps, 4);
                const float inv = 1.f / ps;
#pragma unroll
                for (int m4 = 0; m4 < 4; ++m4)
                    c_lds[bb][kq * 4 + m4] =
                        ev[m4] * inv + b_lds[kq * 4 + m4][p * 2 + jj];
            }
            __syncthreads();
            // s accumulation: S += c[b][k] * u
#pragma unroll
            for (int m = 0; m < 2; ++m)
#pragma unroll
                for (int tt = 0; tt < 8; ++tt) {
                    const int k = wv * 8 + tt;
#pragma unroll
                    for (int r = 0; r < 4; ++r)
                        S[m][tt][r] = fmaf(c_lds[m * 16 + g * 4 + r][k],
                                           C[m][tt][r], S[m][tt][r]);
                }
        }
    }

    float* sp = s_part + (size_t)blockIdx.x * 16384;
#pragma unroll
    for (int m = 0; m < 2; ++m)
#pragma unroll
        for (int tt = 0; tt < 8; ++tt)
#pragma unroll
            for (int r = 0; r < 4; ++r)
                sp[(size_t)(m * 16 + g * 4 + r) * 512 + (wv * 8 + tt) * 16 + z] =
                    S[m][tt][r];
}

// ---------------- ksq: reduce 512 s partials + squash -----------------------
__global__ __launch_bounds__(256)
void ksq(const float* __restrict__ s_part, float* __restrict__ out)
{
    __shared__ f32x4 red[16][16];
    const int tid = threadIdx.x;
    const int c   = blockIdx.x * 16 + (tid & 15);   // c = b*128 + k*4 + zq
    const int ch  = tid >> 4;
    const f32x4* P = reinterpret_cast<const f32x4*>(s_part);
    f32x4 a = (f32x4){0.f, 0.f, 0.f, 0.f};
#pragma unroll 4
    for (int q = 0; q < 32; ++q) a += P[(size_t)(ch * 32 + q) * 4096 + c];
    red[ch][tid & 15] = a;
    __syncthreads();
    if (tid < 16) {
        f32x4 s = (f32x4){0.f, 0.f, 0.f, 0.f};
#pragma unroll
        for (int r = 0; r < 16; ++r) s += red[r][tid];
        float ss = s.x * s.x + s.y * s.y + s.z * s.z + s.w * s.w;
        ss += __shfl_xor(ss, 1);   // zq groups of 4 within lanes 0..15
        ss += __shfl_xor(ss, 2);
        const float n  = sqrtf(ss);
        const float sc = (1.f - 1.f / (__expf(n) + 1e-20f)) / (n + 1e-20f);
        f32x4 o; o.x = s.x * sc; o.y = s.y * sc; o.z = s.z * sc; o.w = s.w * sc;
        reinterpret_cast<f32x4*>(out)[blockIdx.x * 16 + tid] = o;
    }
}

// sentinel if workspace too small
__global__ void k_sentinel(float* __restrict__ out)
{
    out[blockIdx.x * 256 + threadIdx.x] = 12345.0f;
}

extern "C" void kernel_launch(void* const* d_in, const int* in_sizes, int n_in,
                              void* d_out, int out_size, void* d_ws, size_t ws_size,
                              hipStream_t stream)
{
    const float* x    = (const float*)d_in[0];
    const float* w    = (const float*)d_in[1];
    const float* bias = (const float*)d_in[2];
    float* out        = (float*)d_out;

    char* ws = (char*)d_ws;
    if (ws_size < WS_NEED) {
        k_sentinel<<<dim3(64), dim3(256), 0, stream>>>(out);
        return;
    }
    float* t_part = (float*)(ws + WS_TPART);
    float* s_part = (float*)(ws + WS_SPART);
    float* t      = (float*)(ws + WS_T);

    kA    <<<dim3(512), dim3(256), 0, stream>>>(x, w, t_part);
    kred_t<<<dim3(256), dim3(256), 0, stream>>>(t_part, t);
    kB    <<<dim3(512), dim3(256), 0, stream>>>(x, w, t, bias, s_part);
    ksq   <<<dim3(256), dim3(256), 0, stream>>>(s_part, out);
}

// Round 6
// 73.323 us; speedup vs baseline: 1.2561x; 1.2561x over previous
//
#include <hip/hip_runtime.h>

#define NN 2048

typedef __attribute__((ext_vector_type(8))) short short8;   // 8 x bf16
typedef __attribute__((ext_vector_type(4))) float f32x4;

// workspace (bytes):
//  t_part: [512 blk][32b*32k*16z] f32   32 MiB @ 0
//  s_part: [512 blk][32b*32k*16z] f32   32 MiB @ 33554432
//  tp2   : [16][16384] f32              1 MiB  @ 67108864
//  sp2   : [16][16384] f32              1 MiB  @ 68157440
//  t_g   : [ck*16+z][32 b] f32          64 KiB @ 69206016
#define WS_TPART 0UL
#define WS_SPART 33554432UL
#define WS_TP2   67108864UL
#define WS_SP2   68157440UL
#define WS_TG    69206016UL
#define WS_NEED  69271552UL

__device__ __forceinline__ float bf_lo(unsigned v) { return __uint_as_float(v << 16); }
__device__ __forceinline__ float bf_hi(unsigned v) { return __uint_as_float(v & 0xffff0000u); }
__device__ __forceinline__ unsigned pack_bf16(float a, float b) {
    unsigned ua = __float_as_uint(a), ub = __float_as_uint(b);
    return ((ua + 0x8000u) >> 16) | ((ub + 0x8000u) & 0xffff0000u);
}
__device__ __forceinline__ short8 pack8(const float* r) {
    short8 o;
#pragma unroll
    for (int e = 0; e < 8; ++e)
        o[e] = (short)(unsigned short)((__float_as_uint(r[e]) + 0x8000u) >> 16);
    return o;
}
__device__ __forceinline__ short8 sel8(bool keep, short8 v) {
    union { short8 s; unsigned u[4]; } a, b;
    a.s = v;
#pragma unroll
    for (int i = 0; i < 4; ++i) b.u[i] = keep ? a.u[i] : 0u;
    return b.s;
}

// 16-lane (row) rotation reduce on the VALU (DPP) — zero DS-pipe traffic.
__device__ __forceinline__ float dpp_sum16(float v) {
    int a;
    a = __builtin_amdgcn_update_dpp(0, __float_as_int(v), 0x121, 0xf, 0xf, false);
    v += __int_as_float(a);
    a = __builtin_amdgcn_update_dpp(0, __float_as_int(v), 0x122, 0xf, 0xf, false);
    v += __int_as_float(a);
    a = __builtin_amdgcn_update_dpp(0, __float_as_int(v), 0x124, 0xf, 0xf, false);
    v += __int_as_float(a);
    a = __builtin_amdgcn_update_dpp(0, __float_as_int(v), 0x128, 0xf, 0xf, false);
    v += __int_as_float(a);
    return v;
}
__device__ __forceinline__ float dpp_max16(float v) {
    int a;
    a = __builtin_amdgcn_update_dpp(0, __float_as_int(v), 0x121, 0xf, 0xf, false);
    v = fmaxf(v, __int_as_float(a));
    a = __builtin_amdgcn_update_dpp(0, __float_as_int(v), 0x122, 0xf, 0xf, false);
    v = fmaxf(v, __int_as_float(a));
    a = __builtin_amdgcn_update_dpp(0, __float_as_int(v), 0x124, 0xf, 0xf, false);
    v = fmaxf(v, __int_as_float(a));
    a = __builtin_amdgcn_update_dpp(0, __float_as_int(v), 0x128, 0xf, 0xf, false);
    v = fmaxf(v, __int_as_float(a));
    return v;
}

// ---------------- kA: t partials via MFMA (no LDS, no barriers) -------------
// grid 512 (4 j / block), block 512 = 8 waves; wave wv owns ck = wv*4..+4.
// Fragment layouts identical to R5 (numerically verified).
__global__ __launch_bounds__(512)
void kA(const float* __restrict__ x, const float* __restrict__ w,
        float* __restrict__ t_part)
{
    const int tid = threadIdx.x;
    const int wv = tid >> 6, l = tid & 63;
    const int z = l & 15, g = l >> 4;
    const int jl = g >> 1, ih = g & 1;
    const int j0 = blockIdx.x * 4;

    f32x4 C[4][2];
#pragma unroll
    for (int ckl = 0; ckl < 4; ++ckl)
#pragma unroll
        for (int bh = 0; bh < 2; ++bh) C[ckl][bh] = (f32x4){0.f, 0.f, 0.f, 0.f};

#pragma unroll
    for (int p = 0; p < 2; ++p) {
        const int jp = j0 + p * 2 + jl;
        short8 Af[2];
#pragma unroll
        for (int bh = 0; bh < 2; ++bh) {
            const float* xp = x + ((size_t)(bh * 16 + z) * NN + jp) * 16 + ih * 8;
            float ar[8];
            float4 v0 = *reinterpret_cast<const float4*>(xp);
            float4 v1 = *reinterpret_cast<const float4*>(xp + 4);
            ar[0]=v0.x; ar[1]=v0.y; ar[2]=v0.z; ar[3]=v0.w;
            ar[4]=v1.x; ar[5]=v1.y; ar[6]=v1.z; ar[7]=v1.w;
            Af[bh] = pack8(ar);
        }
        short8 Bf[4];
#pragma unroll
        for (int ckl = 0; ckl < 4; ++ckl) {
            const int ck = wv * 4 + ckl;
            const float* wp = w + ((size_t)ck * NN + jp) * 256 + ih * 128 + z;
            float br[8];
#pragma unroll
            for (int e = 0; e < 8; ++e) br[e] = wp[e * 16];
            Bf[ckl] = pack8(br);
        }
#pragma unroll
        for (int ckl = 0; ckl < 4; ++ckl)
#pragma unroll
            for (int bh = 0; bh < 2; ++bh)
                C[ckl][bh] = __builtin_amdgcn_mfma_f32_16x16x32_bf16(
                    Af[bh], Bf[ckl], C[ckl][bh], 0, 0, 0);
    }

    float* tp = t_part + (size_t)blockIdx.x * 16384;
#pragma unroll
    for (int ckl = 0; ckl < 4; ++ckl)
#pragma unroll
        for (int bh = 0; bh < 2; ++bh)
#pragma unroll
            for (int r = 0; r < 4; ++r)
                tp[((bh * 16 + g * 4 + r) * 32 + wv * 4 + ckl) * 16 + z] =
                    C[ckl][bh][r];
}

// ---------------- kred32: sum 32 rows of [512][16384] -> [16][16384] --------
__global__ __launch_bounds__(256)
void kred32(const float* __restrict__ src, float* __restrict__ dst)
{
    const int idx = blockIdx.x * 256 + threadIdx.x;  // 65536
    const int c4 = idx & 4095, ch = idx >> 12;
    const f32x4* P = reinterpret_cast<const f32x4*>(src);
    f32x4 a0 = (f32x4){0,0,0,0}, a1 = a0, a2 = a0, a3 = a0;
#pragma unroll 2
    for (int q = 0; q < 32; q += 4) {
        a0 += P[(size_t)(ch * 32 + q + 0) * 4096 + c4];
        a1 += P[(size_t)(ch * 32 + q + 1) * 4096 + c4];
        a2 += P[(size_t)(ch * 32 + q + 2) * 4096 + c4];
        a3 += P[(size_t)(ch * 32 + q + 3) * 4096 + c4];
    }
    reinterpret_cast<f32x4*>(dst)[(size_t)ch * 4096 + c4] = (a0 + a1) + (a2 + a3);
}

// ---------------- kt2: finish t reduce, emit t_g[ck*16+z][b] ----------------
__global__ __launch_bounds__(256)
void kt2(const float* __restrict__ tp2, float* __restrict__ t_g)
{
    const int c4 = blockIdx.x * 256 + threadIdx.x;   // 4096
    const f32x4* P = reinterpret_cast<const f32x4*>(tp2);
    f32x4 a0 = (f32x4){0,0,0,0}, a1 = a0, a2 = a0, a3 = a0;
#pragma unroll
    for (int q = 0; q < 16; q += 4) {
        a0 += P[(size_t)(q + 0) * 4096 + c4];
        a1 += P[(size_t)(q + 1) * 4096 + c4];
        a2 += P[(size_t)(q + 2) * 4096 + c4];
        a3 += P[(size_t)(q + 3) * 4096 + c4];
    }
    f32x4 s = (a0 + a1) + (a2 + a3);
    const int b = c4 >> 7, ck = (c4 >> 2) & 31, zq = c4 & 3;
#pragma unroll
    for (int e = 0; e < 4; ++e)
        t_g[(size_t)(ck * 16 + zq * 4 + e) * 32 + b] = s[e];
}

// ---------------- kB: recompute u (MFMA regs), logits/softmax/s (DPP) -------
// grid 512 (4 j / block), block 512 = 8 waves.
__global__ __launch_bounds__(512)
void kB(const float* __restrict__ x, const float* __restrict__ w,
        const float* __restrict__ t_g, const float* __restrict__ bias,
        float* __restrict__ s_part)
{
    __shared__ alignas(16) unsigned t_pk[512 * 20];   // [ck*16+z][20] bf16 b-pairs
    __shared__ alignas(16) float l_lds[2][32][34];
    __shared__ alignas(16) float c_lds[2][32][34];

    const int tid = threadIdx.x;
    const int wv = tid >> 6, l = tid & 63;
    const int z = l & 15, g = l >> 4;
    const int jl = g >> 1, ih = g & 1;
    const int j0 = blockIdx.x * 4;

    // stage t -> bf16-packed LDS (pad 20 u32/row: conflict-light, 16B-aligned)
#pragma unroll
    for (int it = 0; it < 4; ++it) {
        const int idx = it * 512 + tid;              // 0..2047
        const int row = idx >> 2, boff = (idx & 3) * 8;
        const float4 v0 = *reinterpret_cast<const float4*>(t_g + (size_t)row * 32 + boff);
        const float4 v1 = *reinterpret_cast<const float4*>(t_g + (size_t)row * 32 + boff + 4);
        uint4 pk;
        pk.x = pack_bf16(v0.x, v0.y);
        pk.y = pack_bf16(v0.z, v0.w);
        pk.z = pack_bf16(v1.x, v1.y);
        pk.w = pack_bf16(v1.z, v1.w);
        *reinterpret_cast<uint4*>(&t_pk[row * 20 + boff / 2]) = pk;
    }
    __syncthreads();

    f32x4 S[4][2];
#pragma unroll
    for (int ckl = 0; ckl < 4; ++ckl)
#pragma unroll
        for (int bh = 0; bh < 2; ++bh) S[ckl][bh] = (f32x4){0.f, 0.f, 0.f, 0.f};

#pragma unroll
    for (int p = 0; p < 2; ++p) {
        const int jp = j0 + p * 2 + jl;
        short8 Af[2];
#pragma unroll
        for (int bh = 0; bh < 2; ++bh) {
            const float* xp = x + ((size_t)(bh * 16 + z) * NN + jp) * 16 + ih * 8;
            float ar[8];
            float4 v0 = *reinterpret_cast<const float4*>(xp);
            float4 v1 = *reinterpret_cast<const float4*>(xp + 4);
            ar[0]=v0.x; ar[1]=v0.y; ar[2]=v0.z; ar[3]=v0.w;
            ar[4]=v1.x; ar[5]=v1.y; ar[6]=v1.z; ar[7]=v1.w;
            Af[bh] = pack8(ar);
        }
        short8 Bf[4];
#pragma unroll
        for (int ckl = 0; ckl < 4; ++ckl) {
            const int ck = wv * 4 + ckl;
            const float* wp = w + ((size_t)ck * NN + jp) * 256 + ih * 128 + z;
            float br[8];
#pragma unroll
            for (int e = 0; e < 8; ++e) br[e] = wp[e * 16];
            Bf[ckl] = pack8(br);
        }

#pragma unroll
        for (int jj = 0; jj < 2; ++jj) {
            const int pp = (p * 2 + jj) & 1;
            const bool keep = (jl == jj);
            const f32x4 zero = (f32x4){0.f, 0.f, 0.f, 0.f};
            f32x4 Cj[4][2];
#pragma unroll
            for (int ckl = 0; ckl < 4; ++ckl) {
                const short8 bsel = sel8(keep, Bf[ckl]);
#pragma unroll
                for (int bh = 0; bh < 2; ++bh)
                    Cj[ckl][bh] = __builtin_amdgcn_mfma_f32_16x16x32_bf16(
                        Af[bh], bsel, zero, 0, 0, 0);
            }
            // logits: pv = u * t, 16-lane DPP z-reduce, masked LDS write
#pragma unroll
            for (int ckl = 0; ckl < 4; ++ckl) {
                const int ck = wv * 4 + ckl;
#pragma unroll
                for (int bh = 0; bh < 2; ++bh) {
                    const uint2 tv = *reinterpret_cast<const uint2*>(
                        &t_pk[(ck * 16 + z) * 20 + bh * 8 + g * 2]);
                    float lr[4];
                    lr[0] = Cj[ckl][bh][0] * bf_lo(tv.x);
                    lr[1] = Cj[ckl][bh][1] * bf_hi(tv.x);
                    lr[2] = Cj[ckl][bh][2] * bf_lo(tv.y);
                    lr[3] = Cj[ckl][bh][3] * bf_hi(tv.y);
#pragma unroll
                    for (int r = 0; r < 4; ++r) lr[r] = dpp_sum16(lr[r]);
                    if (z == ckl * 2 + bh) {
                        const int bb = bh * 16 + g * 4;
                        l_lds[pp][bb + 0][ck] = lr[0];
                        l_lds[pp][bb + 1][ck] = lr[1];
                        l_lds[pp][bb + 2][ck] = lr[2];
                        l_lds[pp][bb + 3][ck] = lr[3];
                    }
                }
            }
            __syncthreads();
            // softmax over k: threads = 32 b x 16 kq; DPP reduces (no DS)
            {
                const int bb = tid >> 4, kq = tid & 15;
                const float lv0 = l_lds[pp][bb][2 * kq];
                const float lv1 = l_lds[pp][bb][2 * kq + 1];
                float m = dpp_max16(fmaxf(lv0, lv1));
                const float e0 = __expf((lv0 - m) * 0.25f);
                const float e1 = __expf((lv1 - m) * 0.25f);
                const float sum = dpp_sum16(e0 + e1);
                const float inv = 1.f / sum;
                const int jg = j0 + p * 2 + jj;
                c_lds[pp][bb][2 * kq]     = e0 * inv + bias[(size_t)(2 * kq) * NN + jg];
                c_lds[pp][bb][2 * kq + 1] = e1 * inv + bias[(size_t)(2 * kq + 1) * NN + jg];
            }
            __syncthreads();
            // s accumulation: u in regs, c via 16-lane LDS broadcast reads
#pragma unroll
            for (int ckl = 0; ckl < 4; ++ckl) {
                const int ck = wv * 4 + ckl;
#pragma unroll
                for (int bh = 0; bh < 2; ++bh) {
                    const int bb = bh * 16 + g * 4;
#pragma unroll
                    for (int r = 0; r < 4; ++r)
                        S[ckl][bh][r] = fmaf(c_lds[pp][bb + r][ck],
                                             Cj[ckl][bh][r], S[ckl][bh][r]);
                }
            }
        }
    }

    float* sp = s_part + (size_t)blockIdx.x * 16384;
#pragma unroll
    for (int ckl = 0; ckl < 4; ++ckl)
#pragma unroll
        for (int bh = 0; bh < 2; ++bh)
#pragma unroll
            for (int r = 0; r < 4; ++r)
                sp[((bh * 16 + g * 4 + r) * 32 + wv * 4 + ckl) * 16 + z] =
                    S[ckl][bh][r];
}

// ---------------- ks2: finish s reduce + squash -----------------------------
__global__ __launch_bounds__(256)
void ks2(const float* __restrict__ sp2, float* __restrict__ out)
{
    const int c4 = blockIdx.x * 256 + threadIdx.x;   // 4096 = b*128 + k*4 + zq
    const f32x4* P = reinterpret_cast<const f32x4*>(sp2);
    f32x4 a0 = (f32x4){0,0,0,0}, a1 = a0, a2 = a0, a3 = a0;
#pragma unroll
    for (int q = 0; q < 16; q += 4) {
        a0 += P[(size_t)(q + 0) * 4096 + c4];
        a1 += P[(size_t)(q + 1) * 4096 + c4];
        a2 += P[(size_t)(q + 2) * 4096 + c4];
        a3 += P[(size_t)(q + 3) * 4096 + c4];
    }
    f32x4 s = (a0 + a1) + (a2 + a3);
    float ss = s.x * s.x + s.y * s.y + s.z * s.z + s.w * s.w;
    ss += __shfl_xor(ss, 1);
    ss += __shfl_xor(ss, 2);
    const float n = sqrtf(ss);
    const float sc = (1.f - 1.f / (__expf(n) + 1e-20f)) / (n + 1e-20f);
    f32x4 o; o.x = s.x * sc; o.y = s.y * sc; o.z = s.z * sc; o.w = s.w * sc;
    reinterpret_cast<f32x4*>(out)[c4] = o;
}

// sentinel if workspace too small
__global__ void k_sentinel(float* __restrict__ out)
{
    out[blockIdx.x * 256 + threadIdx.x] = 12345.0f;
}

extern "C" void kernel_launch(void* const* d_in, const int* in_sizes, int n_in,
                              void* d_out, int out_size, void* d_ws, size_t ws_size,
                              hipStream_t stream)
{
    const float* x    = (const float*)d_in[0];
    const float* w    = (const float*)d_in[1];
    const float* bias = (const float*)d_in[2];
    float* out        = (float*)d_out;

    char* ws = (char*)d_ws;
    if (ws_size < WS_NEED) {
        k_sentinel<<<dim3(64), dim3(256), 0, stream>>>(out);
        return;
    }
    float* t_part = (float*)(ws + WS_TPART);
    float* s_part = (float*)(ws + WS_SPART);
    float* tp2    = (float*)(ws + WS_TP2);
    float* sp2    = (float*)(ws + WS_SP2);
    float* t_g    = (float*)(ws + WS_TG);

    kA    <<<dim3(512), dim3(512), 0, stream>>>(x, w, t_part);
    kred32<<<dim3(256), dim3(256), 0, stream>>>(t_part, tp2);
    kt2   <<<dim3(16),  dim3(256), 0, stream>>>(tp2, t_g);
    kB    <<<dim3(512), dim3(512), 0, stream>>>(x, w, t_g, bias, s_part);
    kred32<<<dim3(256), dim3(256), 0, stream>>>(s_part, sp2);
    ks2   <<<dim3(16),  dim3(256), 0, stream>>>(sp2, out);
}

// Round 8
// 67.309 us; speedup vs baseline: 1.3684x; 1.0894x over previous
//
#include <hip/hip_runtime.h>

#define NN 2048
#define KK 32

typedef __attribute__((ext_vector_type(8))) short short8;   // 8 x bf16
typedef __attribute__((ext_vector_type(4))) float f32x4;

// workspace (bytes):
//  u_pk  : [2048 j][32 b][32 k][8 zp] u32 (bf16 z-pairs)  64 MiB @ 0
//  t_part: [512 blk][32b*32k*16z] f32                     32 MiB @ 67108864
//  tp2   : [16][16384] f32                                 1 MiB @ 100663296
//  t     : [32 b][32 k][16 z] f32                         64 KiB @ 101711872
//  s_part: [32 b][64 jc][512] f32                          4 MiB @ 101777408
#define WS_U     0UL
#define WS_TPART 67108864UL
#define WS_TP2   100663296UL
#define WS_T     101711872UL
#define WS_SPART 101777408UL
#define WS_NEED  105971712UL

__device__ __forceinline__ float bf_lo(unsigned v) { return __uint_as_float(v << 16); }
__device__ __forceinline__ float bf_hi(unsigned v) { return __uint_as_float(v & 0xffff0000u); }
__device__ __forceinline__ unsigned pack_bf16(float a, float b) {
    unsigned ua = __float_as_uint(a), ub = __float_as_uint(b);
    return ((ua + 0x8000u) >> 16) | ((ub + 0x8000u) & 0xffff0000u);
}
__device__ __forceinline__ short8 pack8(const float* r) {
    short8 o;
#pragma unroll
    for (int e = 0; e < 8; ++e)
        o[e] = (short)(unsigned short)((__float_as_uint(r[e]) + 0x8000u) >> 16);
    return o;
}
__device__ __forceinline__ short8 sel8(bool keep, short8 v) {
    union { short8 s; unsigned u[4]; } a, b;
    a.s = v;
#pragma unroll
    for (int i = 0; i < 4; ++i) b.u[i] = keep ? a.u[i] : 0u;
    return b.s;
}

// ---------------- kA2: per-j u (bf16, stored) + t partials via MFMA ---------
// grid 512 (4 j / block), block 512 = 8 waves; wave wv owns k = wv*4..+4.
// OPERAND SWAP vs R5/R6: A = w fragment (M=z), B = x fragment (N=b).
//   A lane (c16=l&15 -> z, g=l>>4 -> (jl,ih)): w[k][jp][ih*8+e][z]
//   B lane (c16 -> b-within-half, g): x[bn*16+c16][jp][ih*8+e]
//   C: row(reg r, g) = z = g*4+r, col = l&15 = b  -> z-pairs are lane-local.
__global__ __launch_bounds__(512)
void kA2(const float* __restrict__ x, const float* __restrict__ w,
         unsigned* __restrict__ u_pk, float* __restrict__ t_part)
{
    const int tid = threadIdx.x;
    const int wv = tid >> 6, l = tid & 63;
    const int c16 = l & 15, g = l >> 4;
    const int jl = g >> 1, ih = g & 1;
    const int j0 = blockIdx.x * 4;

    f32x4 T[4][2];
#pragma unroll
    for (int ckl = 0; ckl < 4; ++ckl)
#pragma unroll
        for (int bn = 0; bn < 2; ++bn) T[ckl][bn] = (f32x4){0.f, 0.f, 0.f, 0.f};

#pragma unroll
    for (int p = 0; p < 2; ++p) {
        const int jp = j0 + p * 2 + jl;

        // A fragments (w): strided dword loads, z = c16
        short8 Wf[4];
#pragma unroll
        for (int ckl = 0; ckl < 4; ++ckl) {
            const int k = wv * 4 + ckl;
            const float* wp = w + ((size_t)k * NN + jp) * 256 + ih * 128 + c16;
            float br[8];
#pragma unroll
            for (int e = 0; e < 8; ++e) br[e] = wp[e * 16];
            Wf[ckl] = pack8(br);
        }
        // B fragments (x): b = bn*16 + c16, 8 contiguous floats
        short8 Xf[2];
#pragma unroll
        for (int bn = 0; bn < 2; ++bn) {
            const float* xp = x + ((size_t)(bn * 16 + c16) * NN + jp) * 16 + ih * 8;
            float ar[8];
            float4 v0 = *reinterpret_cast<const float4*>(xp);
            float4 v1 = *reinterpret_cast<const float4*>(xp + 4);
            ar[0]=v0.x; ar[1]=v0.y; ar[2]=v0.z; ar[3]=v0.w;
            ar[4]=v1.x; ar[5]=v1.y; ar[6]=v1.z; ar[7]=v1.w;
            Xf[bn] = pack8(ar);
        }

#pragma unroll
        for (int jj = 0; jj < 2; ++jj) {
            const bool keep = (jl == jj);
            const int j = j0 + p * 2 + jj;
            const f32x4 zero = (f32x4){0.f, 0.f, 0.f, 0.f};
#pragma unroll
            for (int ckl = 0; ckl < 4; ++ckl) {
                const int k = wv * 4 + ckl;
                const short8 wsel = sel8(keep, Wf[ckl]);
#pragma unroll
                for (int bn = 0; bn < 2; ++bn) {
                    f32x4 Cj = __builtin_amdgcn_mfma_f32_16x16x32_bf16(
                        wsel, Xf[bn], zero, 0, 0, 0);
                    T[ckl][bn] += Cj;
                    // u store: [j][b][k][zp], uint2 = z(g*4..g*4+3) pairs
                    uint2 o;
                    o.x = pack_bf16(Cj[0], Cj[1]);
                    o.y = pack_bf16(Cj[2], Cj[3]);
                    *reinterpret_cast<uint2*>(u_pk +
                        (((size_t)j * 32 + bn * 16 + c16) * 32 + k) * 8 + g * 2) = o;
                }
            }
        }
    }

    // t partials: flat [b*512 + k*16 + z], f32x4 at z-base g*4
    float* tp = t_part + (size_t)blockIdx.x * 16384;
#pragma unroll
    for (int ckl = 0; ckl < 4; ++ckl)
#pragma unroll
        for (int bn = 0; bn < 2; ++bn)
            *reinterpret_cast<f32x4*>(tp + (bn * 16 + c16) * 512 +
                                      (wv * 4 + ckl) * 16 + g * 4) = T[ckl][bn];
}

// ---------------- kred32: sum 32 rows of [512][16384] -> [16][16384] --------
__global__ __launch_bounds__(256)
void kred32(const float* __restrict__ src, float* __restrict__ dst)
{
    const int idx = blockIdx.x * 256 + threadIdx.x;  // 65536
    const int c4 = idx & 4095, ch = idx >> 12;
    const f32x4* P = reinterpret_cast<const f32x4*>(src);
    f32x4 a0 = (f32x4){0,0,0,0}, a1 = a0, a2 = a0, a3 = a0;
#pragma unroll 2
    for (int q = 0; q < 32; q += 4) {
        a0 += P[(size_t)(ch * 32 + q + 0) * 4096 + c4];
        a1 += P[(size_t)(ch * 32 + q + 1) * 4096 + c4];
        a2 += P[(size_t)(ch * 32 + q + 2) * 4096 + c4];
        a3 += P[(size_t)(ch * 32 + q + 3) * 4096 + c4];
    }
    reinterpret_cast<f32x4*>(dst)[(size_t)ch * 4096 + c4] = (a0 + a1) + (a2 + a3);
}

// ---------------- kt2: finish t reduce -> t[b][k][z] (f32) ------------------
__global__ __launch_bounds__(256)
void kt2(const float* __restrict__ tp2, float* __restrict__ t)
{
    const int c4 = blockIdx.x * 256 + threadIdx.x;   // 4096 f32x4 cols
    const f32x4* P = reinterpret_cast<const f32x4*>(tp2);
    f32x4 a0 = (f32x4){0,0,0,0}, a1 = a0, a2 = a0, a3 = a0;
#pragma unroll
    for (int q = 0; q < 16; q += 4) {
        a0 += P[(size_t)(q + 0) * 4096 + c4];
        a1 += P[(size_t)(q + 1) * 4096 + c4];
        a2 += P[(size_t)(q + 2) * 4096 + c4];
        a3 += P[(size_t)(q + 3) * 4096 + c4];
    }
    reinterpret_cast<f32x4*>(t)[c4] = (a0 + a1) + (a2 + a3);
}

// ---------------- kB2: logits + softmax + bias + s-partials (VALU only) -----
// grid 2048 (= 32 b * 64 jc), block 256: k = tid&31, jl = tid>>5.
// u read: [j][b][k][zp] -> 2 uint4 contiguous per (j,b,k); lanes k contiguous 1KB.
__global__ __launch_bounds__(256)
void kB2(const unsigned* __restrict__ u_pk, const float* __restrict__ t,
         const float* __restrict__ bias, float* __restrict__ s_part)
{
    __shared__ float lc_lds[32][33];
    __shared__ float s_lds[8][32][16];
    const int tid = threadIdx.x;
    const int k   = tid & 31;
    const int jl  = tid >> 5;
    const int b   = blockIdx.x >> 6;
    const int jc  = blockIdx.x & 63;

    float tr[16];
    const float4* tp = reinterpret_cast<const float4*>(t + ((size_t)b * KK + k) * 16);
#pragma unroll
    for (int q = 0; q < 4; ++q) {
        float4 v = tp[q];
        tr[4 * q + 0] = v.x; tr[4 * q + 1] = v.y; tr[4 * q + 2] = v.z; tr[4 * q + 3] = v.w;
    }

    uint4 ua[4], ud[4];
#pragma unroll
    for (int jj = 0; jj < 4; ++jj) {
        const int jL = jj * 8 + jl;
        const int jg = jc * 32 + jL;
        const uint4* up = reinterpret_cast<const uint4*>(u_pk)
                        + (((size_t)jg * 32 + b) * 32 + k) * 2;
        ua[jj] = up[0]; ud[jj] = up[1];
        float a0 = 0.f, a1 = 0.f;
        a0 = fmaf(bf_lo(ua[jj].x), tr[0],  a0); a1 = fmaf(bf_hi(ua[jj].x), tr[1],  a1);
        a0 = fmaf(bf_lo(ua[jj].y), tr[2],  a0); a1 = fmaf(bf_hi(ua[jj].y), tr[3],  a1);
        a0 = fmaf(bf_lo(ua[jj].z), tr[4],  a0); a1 = fmaf(bf_hi(ua[jj].z), tr[5],  a1);
        a0 = fmaf(bf_lo(ua[jj].w), tr[6],  a0); a1 = fmaf(bf_hi(ua[jj].w), tr[7],  a1);
        a0 = fmaf(bf_lo(ud[jj].x), tr[8],  a0); a1 = fmaf(bf_hi(ud[jj].x), tr[9],  a1);
        a0 = fmaf(bf_lo(ud[jj].y), tr[10], a0); a1 = fmaf(bf_hi(ud[jj].y), tr[11], a1);
        a0 = fmaf(bf_lo(ud[jj].z), tr[12], a0); a1 = fmaf(bf_hi(ud[jj].z), tr[13], a1);
        a0 = fmaf(bf_lo(ud[jj].w), tr[14], a0); a1 = fmaf(bf_hi(ud[jj].w), tr[15], a1);
        lc_lds[jL][k] = a0 + a1;
    }
    __syncthreads();

    {
        const int jq = tid >> 3, kq = tid & 7;
        float lv[4];
#pragma unroll
        for (int m = 0; m < 4; ++m) lv[m] = lc_lds[jq][kq * 4 + m];
        float pm = fmaxf(fmaxf(lv[0], lv[1]), fmaxf(lv[2], lv[3]));
        pm = fmaxf(pm, __shfl_xor(pm, 1));
        pm = fmaxf(pm, __shfl_xor(pm, 2));
        pm = fmaxf(pm, __shfl_xor(pm, 4));
        float ev[4], ps = 0.f;
#pragma unroll
        for (int m = 0; m < 4; ++m) { ev[m] = __expf((lv[m] - pm) * 0.25f); ps += ev[m]; }
        ps += __shfl_xor(ps, 1);
        ps += __shfl_xor(ps, 2);
        ps += __shfl_xor(ps, 4);
        const float inv = 1.f / ps;
        const int jg = jc * 32 + jq;
#pragma unroll
        for (int m = 0; m < 4; ++m)
            lv[m] = ev[m] * inv + bias[(size_t)(kq * 4 + m) * NN + jg];
        __syncthreads();
#pragma unroll
        for (int m = 0; m < 4; ++m) lc_lds[jq][kq * 4 + m] = lv[m];
    }
    __syncthreads();

    float sacc[16];
#pragma unroll
    for (int z = 0; z < 16; ++z) sacc[z] = 0.f;
#pragma unroll
    for (int jj = 0; jj < 4; ++jj) {
        const float cv = lc_lds[jj * 8 + jl][k];
        const uint4 a = ua[jj], d = ud[jj];
        sacc[0]  = fmaf(cv, bf_lo(a.x), sacc[0]);  sacc[1]  = fmaf(cv, bf_hi(a.x), sacc[1]);
        sacc[2]  = fmaf(cv, bf_lo(a.y), sacc[2]);  sacc[3]  = fmaf(cv, bf_hi(a.y), sacc[3]);
        sacc[4]  = fmaf(cv, bf_lo(a.z), sacc[4]);  sacc[5]  = fmaf(cv, bf_hi(a.z), sacc[5]);
        sacc[6]  = fmaf(cv, bf_lo(a.w), sacc[6]);  sacc[7]  = fmaf(cv, bf_hi(a.w), sacc[7]);
        sacc[8]  = fmaf(cv, bf_lo(d.x), sacc[8]);  sacc[9]  = fmaf(cv, bf_hi(d.x), sacc[9]);
        sacc[10] = fmaf(cv, bf_lo(d.y), sacc[10]); sacc[11] = fmaf(cv, bf_hi(d.y), sacc[11]);
        sacc[12] = fmaf(cv, bf_lo(d.z), sacc[12]); sacc[13] = fmaf(cv, bf_hi(d.z), sacc[13]);
        sacc[14] = fmaf(cv, bf_lo(d.w), sacc[14]); sacc[15] = fmaf(cv, bf_hi(d.w), sacc[15]);
    }

#pragma unroll
    for (int q = 0; q < 4; ++q)
        *reinterpret_cast<float4*>(&s_lds[jl][k][q * 4]) =
            make_float4(sacc[q * 4], sacc[q * 4 + 1], sacc[q * 4 + 2], sacc[q * 4 + 3]);
    __syncthreads();
    {
        const int kk = tid >> 3, zp = tid & 7;
        float2 o; o.x = 0.f; o.y = 0.f;
#pragma unroll
        for (int l2 = 0; l2 < 8; ++l2) {
            o.x += s_lds[l2][kk][2 * zp];
            o.y += s_lds[l2][kk][2 * zp + 1];
        }
        reinterpret_cast<float2*>(s_part)[((size_t)b * 64 + jc) * 256 + kk * 8 + zp] = o;
    }
}

// ---------------- k4: reduce jc slices + squash (float4) --------------------
__global__ __launch_bounds__(256)
void k4_squash(const float* __restrict__ s_part, float* __restrict__ out)
{
    const int idx4 = blockIdx.x * 256 + threadIdx.x;   // 4096 float4s
    const int b = idx4 >> 7, loc4 = idx4 & 127;        // loc4 = k*4 + zq
    const float4* p = reinterpret_cast<const float4*>(s_part) + (size_t)b * 8192 + loc4;
    float4 s = make_float4(0.f, 0.f, 0.f, 0.f);
#pragma unroll 8
    for (int jc = 0; jc < 64; ++jc) {
        float4 v = p[jc * 128];
        s.x += v.x; s.y += v.y; s.z += v.z; s.w += v.w;
    }
    float ss = s.x * s.x + s.y * s.y + s.z * s.z + s.w * s.w;
    ss += __shfl_xor(ss, 1);   // lanes zq 0..3 of same (b,k)
    ss += __shfl_xor(ss, 2);
    const float n = sqrtf(ss);
    const float sc = (1.f - 1.f / (__expf(n) + 1e-20f)) / (n + 1e-20f);
    float4 o; o.x = s.x * sc; o.y = s.y * sc; o.z = s.z * sc; o.w = s.w * sc;
    reinterpret_cast<float4*>(out)[idx4] = o;
}

// sentinel if workspace too small
__global__ void k_sentinel(float* __restrict__ out)
{
    out[blockIdx.x * 256 + threadIdx.x] = 12345.0f;
}

extern "C" void kernel_launch(void* const* d_in, const int* in_sizes, int n_in,
                              void* d_out, int out_size, void* d_ws, size_t ws_size,
                              hipStream_t stream)
{
    const float* x    = (const float*)d_in[0];
    const float* w    = (const float*)d_in[1];
    const float* bias = (const float*)d_in[2];
    float* out        = (float*)d_out;

    char* ws = (char*)d_ws;
    if (ws_size < WS_NEED) {
        k_sentinel<<<dim3(64), dim3(256), 0, stream>>>(out);
        return;
    }
    unsigned* u_pk = (unsigned*)(ws + WS_U);
    float* t_part  = (float*)(ws + WS_TPART);
    float* tp2     = (float*)(ws + WS_TP2);
    float* t       = (float*)(ws + WS_T);
    float* s_part  = (float*)(ws + WS_SPART);

    kA2      <<<dim3(512),  dim3(512), 0, stream>>>(x, w, u_pk, t_part);
    kred32   <<<dim3(256),  dim3(256), 0, stream>>>(t_part, tp2);
    kt2      <<<dim3(16),   dim3(256), 0, stream>>>(tp2, t);
    kB2      <<<dim3(2048), dim3(256), 0, stream>>>(u_pk, t, bias, s_part);
    k4_squash<<<dim3(16),   dim3(256), 0, stream>>>(s_part, out);
}

// Round 9
// 62.050 us; speedup vs baseline: 1.4843x; 1.0848x over previous
//
#include <hip/hip_runtime.h>

#define NN 2048
#define KK 32

typedef __attribute__((ext_vector_type(8))) short short8;   // 8 x bf16
typedef __attribute__((ext_vector_type(4))) float f32x4;

// workspace (bytes):
//  u_pk  : [2048 j][32 b][32 k][8 zp] u32 (bf16 z-pairs)  64 MiB @ 0
//  t_part: [512 blk][32b*32k*16z] f32                     32 MiB @ 67108864
//  tp2   : [16][16384] f32                                 1 MiB @ 100663296
//  t     : [32 b][32 k][16 z] f32                         64 KiB @ 101711872
//  s_part: [32 b][64 jc][512] f32                          4 MiB @ 101777408
#define WS_U     0UL
#define WS_TPART 67108864UL
#define WS_TP2   100663296UL
#define WS_T     101711872UL
#define WS_SPART 101777408UL
#define WS_NEED  105971712UL

__device__ __forceinline__ float bf_lo(unsigned v) { return __uint_as_float(v << 16); }
__device__ __forceinline__ float bf_hi(unsigned v) { return __uint_as_float(v & 0xffff0000u); }
__device__ __forceinline__ unsigned pack_bf16(float a, float b) {
    unsigned ua = __float_as_uint(a), ub = __float_as_uint(b);
    return ((ua + 0x8000u) >> 16) | ((ub + 0x8000u) & 0xffff0000u);
}
__device__ __forceinline__ short8 pack8(const float* r) {
    short8 o;
#pragma unroll
    for (int e = 0; e < 8; ++e)
        o[e] = (short)(unsigned short)((__float_as_uint(r[e]) + 0x8000u) >> 16);
    return o;
}
__device__ __forceinline__ short8 sel8(bool keep, short8 v) {
    union { short8 s; unsigned u[4]; } a, b;
    a.s = v;
#pragma unroll
    for (int i = 0; i < 4; ++i) b.u[i] = keep ? a.u[i] : 0u;
    return b.s;
}

// ---------------- kA2: per-j u (bf16) + t partials via MFMA ------------------
// grid 512 (4 j / block), block 512 = 8 waves; wave wv owns k = wv*4..+4.
// A = w fragment (M=z), B = x fragment (N=b); C: row=z (regs), col=b (lanes).
// u store path: wave-local LDS transpose -> 8 coalesced 512B store instrs per j
// (each instr = 4 x 128B fully-covered segments), replacing 64x8B scatter.
__global__ __launch_bounds__(512)
void kA2(const float* __restrict__ x, const float* __restrict__ w,
         unsigned* __restrict__ u_pk, float* __restrict__ t_part)
{
    __shared__ uint2 xfer[8][32][17];      // per-wave 32b x (4k*4g) + pad
    const int tid = threadIdx.x;
    const int wv = tid >> 6, l = tid & 63;
    const int c16 = l & 15, g = l >> 4;
    const int jl = g >> 1, ih = g & 1;
    const int j0 = blockIdx.x * 4;

    f32x4 T[4][2];
#pragma unroll
    for (int ckl = 0; ckl < 4; ++ckl)
#pragma unroll
        for (int bn = 0; bn < 2; ++bn) T[ckl][bn] = (f32x4){0.f, 0.f, 0.f, 0.f};

#pragma unroll
    for (int p = 0; p < 2; ++p) {
        const int jp = j0 + p * 2 + jl;

        // A fragments (w): strided dword loads, z = c16
        short8 Wf[4];
#pragma unroll
        for (int ckl = 0; ckl < 4; ++ckl) {
            const int k = wv * 4 + ckl;
            const float* wp = w + ((size_t)k * NN + jp) * 256 + ih * 128 + c16;
            float br[8];
#pragma unroll
            for (int e = 0; e < 8; ++e) br[e] = wp[e * 16];
            Wf[ckl] = pack8(br);
        }
        // B fragments (x): b = bn*16 + c16, 8 contiguous floats
        short8 Xf[2];
#pragma unroll
        for (int bn = 0; bn < 2; ++bn) {
            const float* xp = x + ((size_t)(bn * 16 + c16) * NN + jp) * 16 + ih * 8;
            float ar[8];
            float4 v0 = *reinterpret_cast<const float4*>(xp);
            float4 v1 = *reinterpret_cast<const float4*>(xp + 4);
            ar[0]=v0.x; ar[1]=v0.y; ar[2]=v0.z; ar[3]=v0.w;
            ar[4]=v1.x; ar[5]=v1.y; ar[6]=v1.z; ar[7]=v1.w;
            Xf[bn] = pack8(ar);
        }

#pragma unroll
        for (int jj = 0; jj < 2; ++jj) {
            const bool keep = (jl == jj);
            const int j = j0 + p * 2 + jj;
            const f32x4 zero = (f32x4){0.f, 0.f, 0.f, 0.f};

            // 8 MFMA -> Cj[ckl][bn]; accumulate t
            f32x4 Cj[4][2];
#pragma unroll
            for (int ckl = 0; ckl < 4; ++ckl) {
                const short8 wsel = sel8(keep, Wf[ckl]);
#pragma unroll
                for (int bn = 0; bn < 2; ++bn) {
                    Cj[ckl][bn] = __builtin_amdgcn_mfma_f32_16x16x32_bf16(
                        wsel, Xf[bn], zero, 0, 0, 0);
                    T[ckl][bn] += Cj[ckl][bn];
                }
            }

            // wave-local LDS transpose: write (b, ckl*4+g), read store-order
            uint2* xw = &xfer[wv][0][0];
#pragma unroll
            for (int ckl = 0; ckl < 4; ++ckl)
#pragma unroll
                for (int bn = 0; bn < 2; ++bn) {
                    uint2 o;
                    o.x = pack_bf16(Cj[ckl][bn][0], Cj[ckl][bn][1]);
                    o.y = pack_bf16(Cj[ckl][bn][2], Cj[ckl][bn][3]);
                    xw[(bn * 16 + c16) * 17 + ckl * 4 + g] = o;
                }
            // same-wave DS ordering (lgkmcnt) guarantees visibility
            uint2* ubase = reinterpret_cast<uint2*>(u_pk)
                         + (size_t)j * 4096 + wv * 16 + (l & 15);
#pragma unroll
            for (int m = 0; m < 8; ++m) {
                uint2 v = xw[(m * 4 + (l >> 4)) * 17 + (l & 15)];
                ubase[m * 512 + (l >> 4) * 128] = v;
            }
        }
    }

    // t partials: flat [b*512 + k*16 + z], f32x4 at z-base g*4
    float* tp = t_part + (size_t)blockIdx.x * 16384;
#pragma unroll
    for (int ckl = 0; ckl < 4; ++ckl)
#pragma unroll
        for (int bn = 0; bn < 2; ++bn)
            *reinterpret_cast<f32x4*>(tp + (bn * 16 + c16) * 512 +
                                      (wv * 4 + ckl) * 16 + g * 4) = T[ckl][bn];
}

// ---------------- kred32: sum 32 rows of [512][16384] -> [16][16384] --------
__global__ __launch_bounds__(256)
void kred32(const float* __restrict__ src, float* __restrict__ dst)
{
    const int idx = blockIdx.x * 256 + threadIdx.x;  // 65536
    const int c4 = idx & 4095, ch = idx >> 12;
    const f32x4* P = reinterpret_cast<const f32x4*>(src);
    f32x4 a0 = (f32x4){0,0,0,0}, a1 = a0, a2 = a0, a3 = a0;
#pragma unroll 2
    for (int q = 0; q < 32; q += 4) {
        a0 += P[(size_t)(ch * 32 + q + 0) * 4096 + c4];
        a1 += P[(size_t)(ch * 32 + q + 1) * 4096 + c4];
        a2 += P[(size_t)(ch * 32 + q + 2) * 4096 + c4];
        a3 += P[(size_t)(ch * 32 + q + 3) * 4096 + c4];
    }
    reinterpret_cast<f32x4*>(dst)[(size_t)ch * 4096 + c4] = (a0 + a1) + (a2 + a3);
}

// ---------------- kt2: finish t reduce -> t[b][k][z] (f32) ------------------
__global__ __launch_bounds__(256)
void kt2(const float* __restrict__ tp2, float* __restrict__ t)
{
    const int c4 = blockIdx.x * 256 + threadIdx.x;   // 4096 f32x4 cols
    const f32x4* P = reinterpret_cast<const f32x4*>(tp2);
    f32x4 a0 = (f32x4){0,0,0,0}, a1 = a0, a2 = a0, a3 = a0;
#pragma unroll
    for (int q = 0; q < 16; q += 4) {
        a0 += P[(size_t)(q + 0) * 4096 + c4];
        a1 += P[(size_t)(q + 1) * 4096 + c4];
        a2 += P[(size_t)(q + 2) * 4096 + c4];
        a3 += P[(size_t)(q + 3) * 4096 + c4];
    }
    reinterpret_cast<f32x4*>(t)[c4] = (a0 + a1) + (a2 + a3);
}

// ---------------- kB2: logits + softmax + bias + s-partials (VALU only) -----
// grid 2048 (= 32 b * 64 jc), block 256: k = tid&31, jl = tid>>5.
__global__ __launch_bounds__(256)
void kB2(const unsigned* __restrict__ u_pk, const float* __restrict__ t,
         const float* __restrict__ bias, float* __restrict__ s_part)
{
    __shared__ float lc_lds[32][33];
    __shared__ float s_lds[8][32][16];
    const int tid = threadIdx.x;
    const int k   = tid & 31;
    const int jl  = tid >> 5;
    const int b   = blockIdx.x >> 6;
    const int jc  = blockIdx.x & 63;

    float tr[16];
    const float4* tp = reinterpret_cast<const float4*>(t + ((size_t)b * KK + k) * 16);
#pragma unroll
    for (int q = 0; q < 4; ++q) {
        float4 v = tp[q];
        tr[4 * q + 0] = v.x; tr[4 * q + 1] = v.y; tr[4 * q + 2] = v.z; tr[4 * q + 3] = v.w;
    }

    uint4 ua[4], ud[4];
#pragma unroll
    for (int jj = 0; jj < 4; ++jj) {
        const int jL = jj * 8 + jl;
        const int jg = jc * 32 + jL;
        const uint4* up = reinterpret_cast<const uint4*>(u_pk)
                        + (((size_t)jg * 32 + b) * 32 + k) * 2;
        ua[jj] = up[0]; ud[jj] = up[1];
        float a0 = 0.f, a1 = 0.f;
        a0 = fmaf(bf_lo(ua[jj].x), tr[0],  a0); a1 = fmaf(bf_hi(ua[jj].x), tr[1],  a1);
        a0 = fmaf(bf_lo(ua[jj].y), tr[2],  a0); a1 = fmaf(bf_hi(ua[jj].y), tr[3],  a1);
        a0 = fmaf(bf_lo(ua[jj].z), tr[4],  a0); a1 = fmaf(bf_hi(ua[jj].z), tr[5],  a1);
        a0 = fmaf(bf_lo(ua[jj].w), tr[6],  a0); a1 = fmaf(bf_hi(ua[jj].w), tr[7],  a1);
        a0 = fmaf(bf_lo(ud[jj].x), tr[8],  a0); a1 = fmaf(bf_hi(ud[jj].x), tr[9],  a1);
        a0 = fmaf(bf_lo(ud[jj].y), tr[10], a0); a1 = fmaf(bf_hi(ud[jj].y), tr[11], a1);
        a0 = fmaf(bf_lo(ud[jj].z), tr[12], a0); a1 = fmaf(bf_hi(ud[jj].z), tr[13], a1);
        a0 = fmaf(bf_lo(ud[jj].w), tr[14], a0); a1 = fmaf(bf_hi(ud[jj].w), tr[15], a1);
        lc_lds[jL][k] = a0 + a1;
    }
    __syncthreads();

    {
        const int jq = tid >> 3, kq = tid & 7;
        float lv[4];
#pragma unroll
        for (int m = 0; m < 4; ++m) lv[m] = lc_lds[jq][kq * 4 + m];
        float pm = fmaxf(fmaxf(lv[0], lv[1]), fmaxf(lv[2], lv[3]));
        pm = fmaxf(pm, __shfl_xor(pm, 1));
        pm = fmaxf(pm, __shfl_xor(pm, 2));
        pm = fmaxf(pm, __shfl_xor(pm, 4));
        float ev[4], ps = 0.f;
#pragma unroll
        for (int m = 0; m < 4; ++m) { ev[m] = __expf((lv[m] - pm) * 0.25f); ps += ev[m]; }
        ps += __shfl_xor(ps, 1);
        ps += __shfl_xor(ps, 2);
        ps += __shfl_xor(ps, 4);
        const float inv = 1.f / ps;
        const int jg = jc * 32 + jq;
#pragma unroll
        for (int m = 0; m < 4; ++m)
            lv[m] = ev[m] * inv + bias[(size_t)(kq * 4 + m) * NN + jg];
        __syncthreads();
#pragma unroll
        for (int m = 0; m < 4; ++m) lc_lds[jq][kq * 4 + m] = lv[m];
    }
    __syncthreads();

    float sacc[16];
#pragma unroll
    for (int z = 0; z < 16; ++z) sacc[z] = 0.f;
#pragma unroll
    for (int jj = 0; jj < 4; ++jj) {
        const float cv = lc_lds[jj * 8 + jl][k];
        const uint4 a = ua[jj], d = ud[jj];
        sacc[0]  = fmaf(cv, bf_lo(a.x), sacc[0]);  sacc[1]  = fmaf(cv, bf_hi(a.x), sacc[1]);
        sacc[2]  = fmaf(cv, bf_lo(a.y), sacc[2]);  sacc[3]  = fmaf(cv, bf_hi(a.y), sacc[3]);
        sacc[4]  = fmaf(cv, bf_lo(a.z), sacc[4]);  sacc[5]  = fmaf(cv, bf_hi(a.z), sacc[5]);
        sacc[6]  = fmaf(cv, bf_lo(a.w), sacc[6]);  sacc[7]  = fmaf(cv, bf_hi(a.w), sacc[7]);
        sacc[8]  = fmaf(cv, bf_lo(d.x), sacc[8]);  sacc[9]  = fmaf(cv, bf_hi(d.x), sacc[9]);
        sacc[10] = fmaf(cv, bf_lo(d.y), sacc[10]); sacc[11] = fmaf(cv, bf_hi(d.y), sacc[11]);
        sacc[12] = fmaf(cv, bf_lo(d.z), sacc[12]); sacc[13] = fmaf(cv, bf_hi(d.z), sacc[13]);
        sacc[14] = fmaf(cv, bf_lo(d.w), sacc[14]); sacc[15] = fmaf(cv, bf_hi(d.w), sacc[15]);
    }

#pragma unroll
    for (int q = 0; q < 4; ++q)
        *reinterpret_cast<float4*>(&s_lds[jl][k][q * 4]) =
            make_float4(sacc[q * 4], sacc[q * 4 + 1], sacc[q * 4 + 2], sacc[q * 4 + 3]);
    __syncthreads();
    {
        const int kk = tid >> 3, zp = tid & 7;
        float2 o; o.x = 0.f; o.y = 0.f;
#pragma unroll
        for (int l2 = 0; l2 < 8; ++l2) {
            o.x += s_lds[l2][kk][2 * zp];
            o.y += s_lds[l2][kk][2 * zp + 1];
        }
        reinterpret_cast<float2*>(s_part)[((size_t)b * 64 + jc) * 256 + kk * 8 + zp] = o;
    }
}

// ---------------- k4: reduce jc slices + squash (float4) --------------------
__global__ __launch_bounds__(256)
void k4_squash(const float* __restrict__ s_part, float* __restrict__ out)
{
    const int idx4 = blockIdx.x * 256 + threadIdx.x;   // 4096 float4s
    const int b = idx4 >> 7, loc4 = idx4 & 127;        // loc4 = k*4 + zq
    const float4* p = reinterpret_cast<const float4*>(s_part) + (size_t)b * 8192 + loc4;
    float4 s = make_float4(0.f, 0.f, 0.f, 0.f);
#pragma unroll 8
    for (int jc = 0; jc < 64; ++jc) {
        float4 v = p[jc * 128];
        s.x += v.x; s.y += v.y; s.z += v.z; s.w += v.w;
    }
    float ss = s.x * s.x + s.y * s.y + s.z * s.z + s.w * s.w;
    ss += __shfl_xor(ss, 1);   // lanes zq 0..3 of same (b,k)
    ss += __shfl_xor(ss, 2);
    const float n = sqrtf(ss);
    const float sc = (1.f - 1.f / (__expf(n) + 1e-20f)) / (n + 1e-20f);
    float4 o; o.x = s.x * sc; o.y = s.y * sc; o.z = s.z * sc; o.w = s.w * sc;
    reinterpret_cast<float4*>(out)[idx4] = o;
}

// sentinel if workspace too small
__global__ void k_sentinel(float* __restrict__ out)
{
    out[blockIdx.x * 256 + threadIdx.x] = 12345.0f;
}

extern "C" void kernel_launch(void* const* d_in, const int* in_sizes, int n_in,
                              void* d_out, int out_size, void* d_ws, size_t ws_size,
                              hipStream_t stream)
{
    const float* x    = (const float*)d_in[0];
    const float* w    = (const float*)d_in[1];
    const float* bias = (const float*)d_in[2];
    float* out        = (float*)d_out;

    char* ws = (char*)d_ws;
    if (ws_size < WS_NEED) {
        k_sentinel<<<dim3(64), dim3(256), 0, stream>>>(out);
        return;
    }
    unsigned* u_pk = (unsigned*)(ws + WS_U);
    float* t_part  = (float*)(ws + WS_TPART);
    float* tp2     = (float*)(ws + WS_TP2);
    float* t       = (float*)(ws + WS_T);
    float* s_part  = (float*)(ws + WS_SPART);

    kA2      <<<dim3(512),  dim3(512), 0, stream>>>(x, w, u_pk, t_part);
    kred32   <<<dim3(256),  dim3(256), 0, stream>>>(t_part, tp2);
    kt2      <<<dim3(16),   dim3(256), 0, stream>>>(tp2, t);
    kB2      <<<dim3(2048), dim3(256), 0, stream>>>(u_pk, t, bias, s_part);
    k4_squash<<<dim3(16),   dim3(256), 0, stream>>>(s_part, out);
}